// Round 2
// baseline (1761.928 us; speedup 1.0000x reference)
//
#include <hip/hip_runtime.h>

namespace {

constexpr int kB = 512, kD = 64, kP = 16, kT = 500, kH = 128;
constexpr int kKZ = 80;              // D + P (z width)
constexpr int kRows = 16;            // batch rows per block (one MFMA M-tile)
constexpr int kBlocks = kB / kRows;  // 32
constexpr int kThreads = 256;        // 4 waves

// LDS row strides (elements), padded for bank spread / 16B alignment
constexpr int Z0S = 104;  // z planes (96-padded K), u16
constexpr int HS = 136;   // h planes (128 cols), u16
constexpr int STS = 68;   // fp32 state / d1

typedef __attribute__((ext_vector_type(8))) short short8;
typedef __attribute__((ext_vector_type(4))) float float4v;

__device__ __forceinline__ float bf2f(unsigned short u) {
  union { unsigned int i; float f; } v;
  v.i = ((unsigned int)u) << 16;
  return v.f;
}
__device__ __forceinline__ unsigned short f2bf(float f) {  // round-to-nearest-even
  union { float f; unsigned int i; } v;
  v.f = f;
  return (unsigned short)((v.i + 0x7FFFu + ((v.i >> 16) & 1u)) >> 16);
}
__device__ __forceinline__ void split_bf(float x, unsigned short& hi, unsigned short& lo) {
  hi = f2bf(x);
  lo = f2bf(x - bf2f(hi));
}
__device__ __forceinline__ float fast_tanh(float x) {
  // tanh(x) = sign(x) * (1 - 2/(exp2(2|x|*log2e)+1)); exact at 0, saturates to +-1.
  float ax = __builtin_fabsf(x);
  float e = __builtin_amdgcn_exp2f(ax * 2.885390081777927f);  // 2*log2(e)
  float r = 1.0f - 2.0f * __builtin_amdgcn_rcpf(e + 1.0f);
  return __builtin_copysignf(r, x);
}

// MFMA 16x16x32 bf16 layouts (gfx950):
//   A[m][k]: m = lane&15, k = (lane>>4)*8 + j
//   B[k][n]: n = lane&15, k = (lane>>4)*8 + j
//   C/D[m][n]: n = lane&15, m = (lane>>4)*4 + reg
__global__ __launch_bounds__(kThreads, 1) void node_kernel(
    const float* __restrict__ xg, const float* __restrict__ pg,
    const float* __restrict__ w0g, const float* __restrict__ b0g,
    const float* __restrict__ w1g, const float* __restrict__ b1g,
    const float* __restrict__ w2g, const float* __restrict__ b2g,
    float* __restrict__ outg) {
  __shared__ __align__(16) unsigned short zh[kRows * Z0S];
  __shared__ __align__(16) unsigned short zl[kRows * Z0S];
  __shared__ __align__(16) unsigned short h0h[kRows * HS];
  __shared__ __align__(16) unsigned short h0l[kRows * HS];
  __shared__ __align__(16) unsigned short h1h[kRows * HS];
  __shared__ __align__(16) unsigned short h1l[kRows * HS];
  __shared__ __align__(16) float st[kRows * STS];
  __shared__ __align__(16) float d1b[kRows * STS];
  __shared__ __align__(16) float yb[kRows * kD * 8];  // 8-step fp32 output staging

  const int tid = threadIdx.x;
  const int wv = tid >> 6;    // wave 0..3: cols [32w,32w+32) (L0/L1), [16w,16w+16) (L2)
  const int lane = tid & 63;
  const int l15 = lane & 15;
  const int quad = lane >> 4;
  const int brow = blockIdx.x * kRows;

  // ---- persistent split-weight fragments in VGPRs ----
  short8 w0fh[3][2], w0fl[3][2], w1fh[4][2], w1fl[4][2], w2fh[4], w2fl[4];
  {
    const int k0q = quad * 8;
#pragma unroll
    for (int kt = 0; kt < 3; ++kt)
#pragma unroll
      for (int nt = 0; nt < 2; ++nt) {
        short8 vh, vl;
        const int col = wv * 32 + nt * 16 + l15;
#pragma unroll
        for (int j = 0; j < 8; ++j) {
          int k = kt * 32 + k0q + j;
          unsigned short hi = 0, lo = 0;
          if (k < kKZ) split_bf(w0g[k * kH + col], hi, lo);  // zero-pad K 80->96
          vh[j] = (short)hi; vl[j] = (short)lo;
        }
        w0fh[kt][nt] = vh; w0fl[kt][nt] = vl;
      }
#pragma unroll
    for (int kt = 0; kt < 4; ++kt)
#pragma unroll
      for (int nt = 0; nt < 2; ++nt) {
        short8 vh, vl;
        const int col = wv * 32 + nt * 16 + l15;
#pragma unroll
        for (int j = 0; j < 8; ++j) {
          unsigned short hi, lo;
          split_bf(w1g[(kt * 32 + k0q + j) * kH + col], hi, lo);
          vh[j] = (short)hi; vl[j] = (short)lo;
        }
        w1fh[kt][nt] = vh; w1fl[kt][nt] = vl;
      }
#pragma unroll
    for (int kt = 0; kt < 4; ++kt) {
      short8 vh, vl;
      const int col = wv * 16 + l15;
#pragma unroll
      for (int j = 0; j < 8; ++j) {
        unsigned short hi, lo;
        split_bf(w2g[(kt * 32 + k0q + j) * kD + col], hi, lo);
        vh[j] = (short)hi; vl[j] = (short)lo;
      }
      w2fh[kt] = vh; w2fl[kt] = vl;
    }
  }
  float bias0[2], bias1[2];
#pragma unroll
  for (int nt = 0; nt < 2; ++nt) {
    bias0[nt] = b0g[wv * 32 + nt * 16 + l15];
    bias1[nt] = b1g[wv * 32 + nt * 16 + l15];
  }
  const float bias2 = b2g[wv * 16 + l15];

  // ---- state init: c = x[..., 0] ----
  for (int idx = tid; idx < kRows * kD; idx += kThreads) {
    int r = idx >> 6, c = idx & 63;
    float xv = xg[((size_t)(brow + r) * kD + c) * kT];  // t = 0
    st[r * STS + c] = xv;
    unsigned short hi, lo;
    split_bf(xv, hi, lo);
    zh[r * Z0S + c] = hi;
    zl[r * Z0S + c] = lo;
  }
  // zero the z K-pad (cols 80..103): MFMA kt=2 reads k in [64,96)
  for (int idx = tid; idx < kRows * (Z0S - kKZ); idx += kThreads) {
    int r = idx / (Z0S - kKZ), c = idx % (Z0S - kKZ);
    zh[r * Z0S + kKZ + c] = 0;
    zl[r * Z0S + kKZ + c] = 0;
  }
  const int prow = tid >> 4, ppp = tid & 15;  // 16x16 map for p staging
  const size_t pbase = ((size_t)(brow + prow) * kP + ppp) * kT;
  float pv = pg[pbase];  // p[..., 0]
  __syncthreads();

  const int colL2 = wv * 16 + l15;
  for (int t = 0; t < kT; ++t) {
    {  // p columns of z
      unsigned short hi, lo;
      split_bf(pv, hi, lo);
      zh[prow * Z0S + kD + ppp] = hi;
      zl[prow * Z0S + kD + ppp] = lo;
    }
    __syncthreads();  // z complete (state cols from prev step, p now)

    float pvn = 0.0f;
    if (t + 1 < kT) pvn = pg[pbase + t + 1];  // prefetch, hidden by the step

    if ((t & 7) == 0 && t) {  // burst previous 8-step output tile
      const int t0 = t - 8;
#pragma unroll
      for (int q2 = 0; q2 < 4; ++q2) {
        int idx = tid + q2 * kThreads;
        int r = idx >> 6, c = idx & 63;
        const float4v* src = (const float4v*)&yb[(r * kD + c) * 8];
        float4v lo = src[0], hi = src[1];
        float* dst = outg + ((size_t)(brow + r) * kD + c) * kT + t0;  // 16B-aligned
        *(float4v*)(dst) = lo;
        *(float4v*)(dst + 4) = hi;
      }
    }

#pragma unroll
    for (int ev = 0; ev < 2; ++ev) {  // Heun: eval1 at c, eval2 at c+d1
      // ---- L0: z[16x96] @ W0[96x128], split product hi*hi + hi*lo + lo*hi ----
      short8 a0h[3], a0l[3];
#pragma unroll
      for (int kt = 0; kt < 3; ++kt) {
        a0h[kt] = *(const short8*)&zh[l15 * Z0S + kt * 32 + quad * 8];
        a0l[kt] = *(const short8*)&zl[l15 * Z0S + kt * 32 + quad * 8];
      }
#pragma unroll
      for (int nt = 0; nt < 2; ++nt) {
        float4v ac = {bias0[nt], bias0[nt], bias0[nt], bias0[nt]};
#pragma unroll
        for (int kt = 0; kt < 3; ++kt) {
          ac = __builtin_amdgcn_mfma_f32_16x16x32_bf16(a0h[kt], w0fh[kt][nt], ac, 0, 0, 0);
          ac = __builtin_amdgcn_mfma_f32_16x16x32_bf16(a0h[kt], w0fl[kt][nt], ac, 0, 0, 0);
          ac = __builtin_amdgcn_mfma_f32_16x16x32_bf16(a0l[kt], w0fh[kt][nt], ac, 0, 0, 0);
        }
        const int col = wv * 32 + nt * 16 + l15;
#pragma unroll
        for (int r = 0; r < 4; ++r) {
          unsigned short hi, lo;
          split_bf(fast_tanh(ac[r]), hi, lo);
          h0h[(quad * 4 + r) * HS + col] = hi;
          h0l[(quad * 4 + r) * HS + col] = lo;
        }
      }
      __syncthreads();
      // ---- L1: h0[16x128] @ W1[128x128] ----
      short8 a1h[4], a1l[4];
#pragma unroll
      for (int kt = 0; kt < 4; ++kt) {
        a1h[kt] = *(const short8*)&h0h[l15 * HS + kt * 32 + quad * 8];
        a1l[kt] = *(const short8*)&h0l[l15 * HS + kt * 32 + quad * 8];
      }
#pragma unroll
      for (int nt = 0; nt < 2; ++nt) {
        float4v ac = {bias1[nt], bias1[nt], bias1[nt], bias1[nt]};
#pragma unroll
        for (int kt = 0; kt < 4; ++kt) {
          ac = __builtin_amdgcn_mfma_f32_16x16x32_bf16(a1h[kt], w1fh[kt][nt], ac, 0, 0, 0);
          ac = __builtin_amdgcn_mfma_f32_16x16x32_bf16(a1h[kt], w1fl[kt][nt], ac, 0, 0, 0);
          ac = __builtin_amdgcn_mfma_f32_16x16x32_bf16(a1l[kt], w1fh[kt][nt], ac, 0, 0, 0);
        }
        const int col = wv * 32 + nt * 16 + l15;
#pragma unroll
        for (int r = 0; r < 4; ++r) {
          unsigned short hi, lo;
          split_bf(fast_tanh(ac[r]), hi, lo);
          h1h[(quad * 4 + r) * HS + col] = hi;
          h1l[(quad * 4 + r) * HS + col] = lo;
        }
      }
      __syncthreads();
      // ---- L2: h1[16x128] @ W2[128x64] (wave w -> cols [16w,16w+16)) ----
      short8 a2h[4], a2l[4];
#pragma unroll
      for (int kt = 0; kt < 4; ++kt) {
        a2h[kt] = *(const short8*)&h1h[l15 * HS + kt * 32 + quad * 8];
        a2l[kt] = *(const short8*)&h1l[l15 * HS + kt * 32 + quad * 8];
      }
      float4v ac = {bias2, bias2, bias2, bias2};
#pragma unroll
      for (int kt = 0; kt < 4; ++kt) {
        ac = __builtin_amdgcn_mfma_f32_16x16x32_bf16(a2h[kt], w2fh[kt], ac, 0, 0, 0);
        ac = __builtin_amdgcn_mfma_f32_16x16x32_bf16(a2h[kt], w2fl[kt], ac, 0, 0, 0);
        ac = __builtin_amdgcn_mfma_f32_16x16x32_bf16(a2l[kt], w2fh[kt], ac, 0, 0, 0);
      }

      if (ev == 0) {
#pragma unroll
        for (int r = 0; r < 4; ++r) {
          const int row = quad * 4 + r;
          float c = st[row * STS + colL2];
          d1b[row * STS + colL2] = ac[r];
          float xi = c + ac[r];  // dt = 1
          unsigned short hi, lo;
          split_bf(xi, hi, lo);
          zh[row * Z0S + colL2] = hi;
          zl[row * Z0S + colL2] = lo;
        }
        __syncthreads();  // xi visible to all waves for eval2's L0
      } else {
#pragma unroll
        for (int r = 0; r < 4; ++r) {
          const int row = quad * 4 + r;
          float c = st[row * STS + colL2];
          float nx = c + 0.5f * (ac[r] + d1b[row * STS + colL2]);
          yb[(row * kD + colL2) * 8 + (t & 7)] = c;  // emit PREVIOUS state
          st[row * STS + colL2] = nx;
          unsigned short hi, lo;
          split_bf(nx, hi, lo);
          zh[row * Z0S + colL2] = hi;
          zl[row * Z0S + colL2] = lo;
        }
        // no barrier: next iteration's top sync covers these stores
      }
    }
    pv = pvn;
  }
  __syncthreads();
  // tail flush: t = 496..499 (slots 0..3 of the last tile)
  {
    const int t0 = (kT / 8) * 8;  // 496
#pragma unroll
    for (int q2 = 0; q2 < 4; ++q2) {
      int idx = tid + q2 * kThreads;
      int r = idx >> 6, c = idx & 63;
      const float4v* src = (const float4v*)&yb[(r * kD + c) * 8];
      float* dst = outg + ((size_t)(brow + r) * kD + c) * kT + t0;
      *(float4v*)(dst) = src[0];
    }
  }
}

}  // namespace

extern "C" void kernel_launch(void* const* d_in, const int* in_sizes, int n_in,
                              void* d_out, int out_size, void* d_ws, size_t ws_size,
                              hipStream_t stream) {
  const float* xg = (const float*)d_in[0];   // x [512,64,500]
  const float* pg = (const float*)d_in[1];   // p [512,16,500]
  // d_in[2] = i_ext (unused by Simple_MLP)
  const float* w0g = (const float*)d_in[3];  // W0 [80,128]
  const float* b0g = (const float*)d_in[4];  // b0 [128]
  const float* w1g = (const float*)d_in[5];  // W1 [128,128]
  const float* b1g = (const float*)d_in[6];  // b1 [128]
  const float* w2g = (const float*)d_in[7];  // W2 [128,64]
  const float* b2g = (const float*)d_in[8];  // b2 [64]
  float* outg = (float*)d_out;               // [512,64,500] fp32

  hipLaunchKernelGGL(node_kernel, dim3(kBlocks), dim3(kThreads), 0, stream,
                     xg, pg, w0g, b0g, w1g, b1g, w2g, b2g, outg);
}

// Round 3
// 1716.024 us; speedup vs baseline: 1.0268x; 1.0268x over previous
//
#include <hip/hip_runtime.h>

namespace {

constexpr int kB = 512, kD = 64, kP = 16, kT = 500, kH = 128;
constexpr int kKZ = 80;              // D + P (z width)
constexpr int kRows = 16;            // batch rows per block (one MFMA M-tile)
constexpr int kBlocks = kB / kRows;  // 32
constexpr int kThreads = 256;        // 4 waves

// LDS row strides (u16 elements). Writes use a k-chunk XOR-2 swizzle for
// rows >= 8 so ds_write_b16 lands 2-way (free) instead of 4-way.
constexpr int Z0S = 104;  // z planes: 12 used 16B chunks + pad
constexpr int HS = 136;   // h planes: 16 chunks + pad
constexpr int YS = 68;    // yb fp32 row stride

typedef __attribute__((ext_vector_type(8))) short short8;
typedef __attribute__((ext_vector_type(4))) float float4v;

__device__ __forceinline__ float bf2f(unsigned short u) {
  union { unsigned int i; float f; } v;
  v.i = ((unsigned int)u) << 16;
  return v.f;
}
__device__ __forceinline__ unsigned short f2bf(float f) {  // RNE
  union { float f; unsigned int i; } v;
  v.f = f;
  return (unsigned short)((v.i + 0x7FFFu + ((v.i >> 16) & 1u)) >> 16);
}
__device__ __forceinline__ void split_bf(float x, unsigned short& hi, unsigned short& lo) {
  hi = f2bf(x);
  lo = f2bf(x - bf2f(hi));
}
#if __has_builtin(__builtin_amdgcn_cvt_pk_bf16_f32)
__device__ __forceinline__ unsigned int pk_bf16(float a, float b) {
  auto v = __builtin_amdgcn_cvt_pk_bf16_f32(a, b);
  unsigned int u;
  __builtin_memcpy(&u, &v, 4);
  return u;
}
#else
__device__ __forceinline__ unsigned int pk_bf16(float a, float b) {
  return (unsigned int)f2bf(a) | ((unsigned int)f2bf(b) << 16);
}
#endif
__device__ __forceinline__ void split2(float x, unsigned short& hi, unsigned short& lo) {
  unsigned int uh = pk_bf16(x, x);
  float hif;
  { unsigned int tb = uh << 16; __builtin_memcpy(&hif, &tb, 4); }
  float lof = x - hif;
  unsigned int ul = pk_bf16(lof, lof);
  hi = (unsigned short)uh;
  lo = (unsigned short)ul;
}
__device__ __forceinline__ float fast_tanh(float x) {
  float ax = __builtin_fabsf(x);
  float e = __builtin_amdgcn_exp2f(ax * 2.885390081777927f);  // 2*log2(e)
  float r = 1.0f - 2.0f * __builtin_amdgcn_rcpf(e + 1.0f);
  return __builtin_copysignf(r, x);
}

// MFMA 16x16x32 bf16 layouts (gfx950):
//   A[m][k]: m = lane&15, k = (lane>>4)*8 + j
//   B[k][n]: n = lane&15, k = (lane>>4)*8 + j
//   C/D[m][n]: n = lane&15, m = (lane>>4)*4 + reg
__global__ __launch_bounds__(kThreads, 1) void node_kernel(
    const float* __restrict__ xg, const float* __restrict__ pg,
    const float* __restrict__ w0g, const float* __restrict__ b0g,
    const float* __restrict__ w1g, const float* __restrict__ b1g,
    const float* __restrict__ w2g, const float* __restrict__ b2g,
    float* __restrict__ outg) {
  __shared__ __align__(16) unsigned short zh[kRows * Z0S];
  __shared__ __align__(16) unsigned short zl[kRows * Z0S];
  __shared__ __align__(16) unsigned short h0h[kRows * HS];
  __shared__ __align__(16) unsigned short h0l[kRows * HS];
  __shared__ __align__(16) unsigned short h1h[kRows * HS];
  __shared__ __align__(16) unsigned short h1l[kRows * HS];
  __shared__ __align__(16) float yb[8][kRows * YS];  // 8-step output staging

  const int tid = threadIdx.x;
  const int wv = tid >> 6;    // wave: cols [32w,32w+32) (L0/L1), [16w,16w+16) (L2)
  const int lane = tid & 63;
  const int l15 = lane & 15;
  const int quad = lane >> 4;
  const int brow = blockIdx.x * kRows;
  const int rswz = (quad & 2) ? 2 : 0;       // writer chunk swizzle (rows = quad*4+r)
  const int asw = (l15 & 8) ? 2 : 0;         // A-frag reader chunk swizzle (row = l15)

  // ---- persistent split-weight fragments in VGPRs ----
  short8 w0fh[3][2], w0fl[3][2], w1fh[4][2], w1fl[4][2], w2fh[4], w2fl[4];
  {
    const int k0q = quad * 8;
#pragma unroll
    for (int kt = 0; kt < 3; ++kt)
#pragma unroll
      for (int nt = 0; nt < 2; ++nt) {
        short8 vh, vl;
        const int col = wv * 32 + nt * 16 + l15;
#pragma unroll
        for (int j = 0; j < 8; ++j) {
          int k = kt * 32 + k0q + j;
          unsigned short hi = 0, lo = 0;
          if (k < kKZ) split_bf(w0g[k * kH + col], hi, lo);  // zero-pad K 80->96
          vh[j] = (short)hi; vl[j] = (short)lo;
        }
        w0fh[kt][nt] = vh; w0fl[kt][nt] = vl;
      }
#pragma unroll
    for (int kt = 0; kt < 4; ++kt)
#pragma unroll
      for (int nt = 0; nt < 2; ++nt) {
        short8 vh, vl;
        const int col = wv * 32 + nt * 16 + l15;
#pragma unroll
        for (int j = 0; j < 8; ++j) {
          unsigned short hi, lo;
          split_bf(w1g[(kt * 32 + k0q + j) * kH + col], hi, lo);
          vh[j] = (short)hi; vl[j] = (short)lo;
        }
        w1fh[kt][nt] = vh; w1fl[kt][nt] = vl;
      }
#pragma unroll
    for (int kt = 0; kt < 4; ++kt) {
      short8 vh, vl;
      const int col = wv * 16 + l15;
#pragma unroll
      for (int j = 0; j < 8; ++j) {
        unsigned short hi, lo;
        split_bf(w2g[(kt * 32 + k0q + j) * kD + col], hi, lo);
        vh[j] = (short)hi; vl[j] = (short)lo;
      }
      w2fh[kt] = vh; w2fl[kt] = vl;
    }
  }
  float bias0[2], bias1[2];
#pragma unroll
  for (int nt = 0; nt < 2; ++nt) {
    bias0[nt] = b0g[wv * 32 + nt * 16 + l15];
    bias1[nt] = b1g[wv * 32 + nt * 16 + l15];
  }
  const float bias2 = b2g[wv * 16 + l15];
  const int colL2 = wv * 16 + l15;

  // ---- per-lane fp32 state registers (C/D layout: rows quad*4+r, col colL2) ----
  float stR[4], d1R[4];
#pragma unroll
  for (int r = 0; r < 4; ++r)
    stR[r] = xg[((size_t)(brow + quad * 4 + r) * kD + colL2) * kT];  // t = 0

  // ---- LDS init: z state cols (swizzled), zero p/pad region ----
  for (int idx = tid; idx < kRows * kD; idx += kThreads) {
    int r = idx >> 6, c = idx & 63;
    float xv = xg[((size_t)(brow + r) * kD + c) * kT];
    unsigned short hi, lo;
    split_bf(xv, hi, lo);
    int off = r * Z0S + ((((c >> 3) ^ ((r & 8) ? 2 : 0)) << 3) | (c & 7));
    zh[off] = hi;
    zl[off] = lo;
  }
  for (int idx = tid; idx < kRows * 40; idx += kThreads) {  // physical cols 64..103
    int r = idx / 40, c = idx % 40;
    zh[r * Z0S + kD + c] = 0;
    zl[r * Z0S + kD + c] = 0;
  }
  const int prow = tid >> 4, ppp = tid & 15;  // 16x16 map for p staging
  const size_t pbase = ((size_t)(brow + prow) * kP + ppp) * kT;
  const int poff = prow * Z0S + ((((8 + (ppp >> 3)) ^ ((prow & 8) ? 2 : 0)) << 3) | (ppp & 7));
  float pv = pg[pbase];  // p[..., 0]
  __syncthreads();

  for (int t = 0; t < kT; ++t) {
    {  // p columns of z (swizzled chunk)
      unsigned short hi, lo;
      split2(pv, hi, lo);
      zh[poff] = hi;
      zl[poff] = lo;
    }
    __syncthreads();  // z complete (state cols from prev step, p now)

    float pvn = 0.0f;
    if (t + 1 < kT) pvn = pg[pbase + t + 1];  // prefetch, hidden by the step

    if ((t & 7) == 0 && t) {  // burst previous 8-step output tile
      const int t0 = t - 8;
#pragma unroll
      for (int q2 = 0; q2 < 4; ++q2) {
        int idx = tid + q2 * kThreads;
        int r = idx >> 6, c = idx & 63;
        float v[8];
#pragma unroll
        for (int s = 0; s < 8; ++s) v[s] = yb[s][r * YS + c];
        float* dst = outg + ((size_t)(brow + r) * kD + c) * kT + t0;  // 16B-aligned
        float4v vlo = {v[0], v[1], v[2], v[3]}, vhi = {v[4], v[5], v[6], v[7]};
        *(float4v*)(dst) = vlo;
        *(float4v*)(dst + 4) = vhi;
      }
    }

#pragma unroll
    for (int ev = 0; ev < 2; ++ev) {  // Heun: eval1 at c, eval2 at c+d1
      // ---- L0: z[16x96] @ W0[96x128], 3 split-product accumulator chains ----
      short8 a0h[3], a0l[3];
#pragma unroll
      for (int kt = 0; kt < 3; ++kt) {
        const int off = l15 * Z0S + (((kt * 4 + quad) ^ asw) << 3);
        a0h[kt] = *(const short8*)&zh[off];
        a0l[kt] = *(const short8*)&zl[off];
      }
#pragma unroll
      for (int nt = 0; nt < 2; ++nt) {
        float4v ahh = {bias0[nt], bias0[nt], bias0[nt], bias0[nt]};
        float4v ahl = {0.f, 0.f, 0.f, 0.f}, alh = {0.f, 0.f, 0.f, 0.f};
#pragma unroll
        for (int kt = 0; kt < 3; ++kt) {
          ahh = __builtin_amdgcn_mfma_f32_16x16x32_bf16(a0h[kt], w0fh[kt][nt], ahh, 0, 0, 0);
          ahl = __builtin_amdgcn_mfma_f32_16x16x32_bf16(a0h[kt], w0fl[kt][nt], ahl, 0, 0, 0);
          alh = __builtin_amdgcn_mfma_f32_16x16x32_bf16(a0l[kt], w0fh[kt][nt], alh, 0, 0, 0);
        }
        float4v ac = ahh + (ahl + alh);
        const int cb = wv * 4 + nt * 2 + (l15 >> 3);
        const int off = (((cb ^ rswz) << 3) | (l15 & 7));
#pragma unroll
        for (int r = 0; r < 4; ++r) {
          unsigned short hi, lo;
          split2(fast_tanh(ac[r]), hi, lo);
          h0h[(quad * 4 + r) * HS + off] = hi;
          h0l[(quad * 4 + r) * HS + off] = lo;
        }
      }
      __syncthreads();
      // ---- L1: h0[16x128] @ W1[128x128] ----
      short8 a1h[4], a1l[4];
#pragma unroll
      for (int kt = 0; kt < 4; ++kt) {
        const int off = l15 * HS + (((kt * 4 + quad) ^ asw) << 3);
        a1h[kt] = *(const short8*)&h0h[off];
        a1l[kt] = *(const short8*)&h0l[off];
      }
#pragma unroll
      for (int nt = 0; nt < 2; ++nt) {
        float4v ahh = {bias1[nt], bias1[nt], bias1[nt], bias1[nt]};
        float4v ahl = {0.f, 0.f, 0.f, 0.f}, alh = {0.f, 0.f, 0.f, 0.f};
#pragma unroll
        for (int kt = 0; kt < 4; ++kt) {
          ahh = __builtin_amdgcn_mfma_f32_16x16x32_bf16(a1h[kt], w1fh[kt][nt], ahh, 0, 0, 0);
          ahl = __builtin_amdgcn_mfma_f32_16x16x32_bf16(a1h[kt], w1fl[kt][nt], ahl, 0, 0, 0);
          alh = __builtin_amdgcn_mfma_f32_16x16x32_bf16(a1l[kt], w1fh[kt][nt], alh, 0, 0, 0);
        }
        float4v ac = ahh + (ahl + alh);
        const int cb = wv * 4 + nt * 2 + (l15 >> 3);
        const int off = (((cb ^ rswz) << 3) | (l15 & 7));
#pragma unroll
        for (int r = 0; r < 4; ++r) {
          unsigned short hi, lo;
          split2(fast_tanh(ac[r]), hi, lo);
          h1h[(quad * 4 + r) * HS + off] = hi;
          h1l[(quad * 4 + r) * HS + off] = lo;
        }
      }
      __syncthreads();
      // ---- L2: h1[16x128] @ W2[128x64] (wave w -> cols [16w,16w+16)) ----
      short8 a2h[4], a2l[4];
#pragma unroll
      for (int kt = 0; kt < 4; ++kt) {
        const int off = l15 * HS + (((kt * 4 + quad) ^ asw) << 3);
        a2h[kt] = *(const short8*)&h1h[off];
        a2l[kt] = *(const short8*)&h1l[off];
      }
      float4v ahh = {bias2, bias2, bias2, bias2};
      float4v ahl = {0.f, 0.f, 0.f, 0.f}, alh = {0.f, 0.f, 0.f, 0.f};
#pragma unroll
      for (int kt = 0; kt < 4; ++kt) {
        ahh = __builtin_amdgcn_mfma_f32_16x16x32_bf16(a2h[kt], w2fh[kt], ahh, 0, 0, 0);
        ahl = __builtin_amdgcn_mfma_f32_16x16x32_bf16(a2h[kt], w2fl[kt], ahl, 0, 0, 0);
        alh = __builtin_amdgcn_mfma_f32_16x16x32_bf16(a2l[kt], w2fh[kt], alh, 0, 0, 0);
      }
      float4v ac = ahh + (ahl + alh);

      const int zcb = wv * 2 + (l15 >> 3);
      const int zoff = (((zcb ^ rswz) << 3) | (l15 & 7));
      if (ev == 0) {
#pragma unroll
        for (int r = 0; r < 4; ++r) {
          d1R[r] = ac[r];
          float xi = stR[r] + ac[r];  // dt = 1
          unsigned short hi, lo;
          split2(xi, hi, lo);
          zh[(quad * 4 + r) * Z0S + zoff] = hi;
          zl[(quad * 4 + r) * Z0S + zoff] = lo;
        }
        __syncthreads();  // xi visible to all waves for eval2's L0
      } else {
#pragma unroll
        for (int r = 0; r < 4; ++r) {
          float c = stR[r];
          float nx = c + 0.5f * (ac[r] + d1R[r]);
          yb[t & 7][(quad * 4 + r) * YS + colL2] = c;  // emit PREVIOUS state
          stR[r] = nx;
          unsigned short hi, lo;
          split2(nx, hi, lo);
          zh[(quad * 4 + r) * Z0S + zoff] = hi;
          zl[(quad * 4 + r) * Z0S + zoff] = lo;
        }
        // no barrier: next iteration's top sync covers these stores
      }
    }
    pv = pvn;
  }
  __syncthreads();
  // tail flush: t = 496..499 (slots 0..3 of the last tile)
  {
    const int t0 = (kT / 8) * 8;  // 496
#pragma unroll
    for (int q2 = 0; q2 < 4; ++q2) {
      int idx = tid + q2 * kThreads;
      int r = idx >> 6, c = idx & 63;
      float v[4];
#pragma unroll
      for (int s = 0; s < 4; ++s) v[s] = yb[s][r * YS + c];
      float* dst = outg + ((size_t)(brow + r) * kD + c) * kT + t0;
      float4v vv = {v[0], v[1], v[2], v[3]};
      *(float4v*)(dst) = vv;
    }
  }
}

}  // namespace

extern "C" void kernel_launch(void* const* d_in, const int* in_sizes, int n_in,
                              void* d_out, int out_size, void* d_ws, size_t ws_size,
                              hipStream_t stream) {
  const float* xg = (const float*)d_in[0];   // x [512,64,500]
  const float* pg = (const float*)d_in[1];   // p [512,16,500]
  // d_in[2] = i_ext (unused by Simple_MLP)
  const float* w0g = (const float*)d_in[3];  // W0 [80,128]
  const float* b0g = (const float*)d_in[4];  // b0 [128]
  const float* w1g = (const float*)d_in[5];  // W1 [128,128]
  const float* b1g = (const float*)d_in[6];  // b1 [128]
  const float* w2g = (const float*)d_in[7];  // W2 [128,64]
  const float* b2g = (const float*)d_in[8];  // b2 [64]
  float* outg = (float*)d_out;               // [512,64,500] fp32

  hipLaunchKernelGGL(node_kernel, dim3(kBlocks), dim3(kThreads), 0, stream,
                     xg, pg, w0g, b0g, w1g, b1g, w2g, b2g, outg);
}

// Round 4
// 1325.175 us; speedup vs baseline: 1.3296x; 1.2949x over previous
//
#include <hip/hip_runtime.h>

namespace {

constexpr int kB = 512, kD = 64, kP = 16, kT = 500, kH = 128;
constexpr int kKZ = 80;              // D + P (z width)
constexpr int kRows = 16;            // batch rows per block (one MFMA M-tile)
constexpr int kBlocks = kB / kRows;  // 32
constexpr int kThreads = 256;        // 4 waves

// LDS row strides (u16 elements). Writes use a k-chunk XOR-2 swizzle for
// rows >= 8 so ds_write_b16 lands 2-way instead of 4-way.
constexpr int Z0S = 104;  // z planes: 12 used 16B chunks + pad
constexpr int HS = 136;   // h planes: 16 chunks + pad
constexpr int YS = 68;    // yb fp32 row stride

typedef __attribute__((ext_vector_type(8))) short short8;
typedef __attribute__((ext_vector_type(4))) float float4v;

__device__ __forceinline__ float bf2f(unsigned short u) {
  union { unsigned int i; float f; } v;
  v.i = ((unsigned int)u) << 16;
  return v.f;
}
__device__ __forceinline__ unsigned short f2bf(float f) {  // RNE
  union { float f; unsigned int i; } v;
  v.f = f;
  return (unsigned short)((v.i + 0x7FFFu + ((v.i >> 16) & 1u)) >> 16);
}
__device__ __forceinline__ void split_bf(float x, unsigned short& hi, unsigned short& lo) {
  hi = f2bf(x);
  lo = f2bf(x - bf2f(hi));
}
#if __has_builtin(__builtin_amdgcn_cvt_pk_bf16_f32)
__device__ __forceinline__ unsigned int pk_bf16(float a, float b) {
  auto v = __builtin_amdgcn_cvt_pk_bf16_f32(a, b);
  unsigned int u;
  __builtin_memcpy(&u, &v, 4);
  return u;
}
#else
__device__ __forceinline__ unsigned int pk_bf16(float a, float b) {
  return (unsigned int)f2bf(a) | ((unsigned int)f2bf(b) << 16);
}
#endif
__device__ __forceinline__ unsigned short f2bf1(float x) {  // 1-instr RNE round
  return (unsigned short)pk_bf16(x, x);
}
__device__ __forceinline__ void split2(float x, unsigned short& hi, unsigned short& lo) {
  unsigned int uh = pk_bf16(x, x);
  float hif;
  { unsigned int tb = uh << 16; __builtin_memcpy(&hif, &tb, 4); }
  hi = (unsigned short)uh;
  lo = (unsigned short)pk_bf16(x - hif, x - hif);
}
__device__ __forceinline__ float fast_tanh(float x) {
  // 1 - 2/(e^{2x}+1): exact saturation both ends, no NaN, 5 VALU.
  float e = __builtin_amdgcn_exp2f(x * 2.885390081777927f);  // 2*log2(e)
  return 1.0f - 2.0f * __builtin_amdgcn_rcpf(e + 1.0f);
}

// MFMA 16x16x32 bf16 layouts (gfx950):
//   A[m][k]: m = lane&15, k = (lane>>4)*8 + j
//   B[k][n]: n = lane&15, k = (lane>>4)*8 + j
//   C/D[m][n]: n = lane&15, m = (lane>>4)*4 + reg
__global__ __launch_bounds__(kThreads, 1) void node_kernel(
    const float* __restrict__ xg, const float* __restrict__ pg,
    const float* __restrict__ w0g, const float* __restrict__ b0g,
    const float* __restrict__ w1g, const float* __restrict__ b1g,
    const float* __restrict__ w2g, const float* __restrict__ b2g,
    float* __restrict__ outg) {
  __shared__ __align__(16) unsigned short zh[kRows * Z0S];
  __shared__ __align__(16) unsigned short zl[kRows * Z0S];
  __shared__ __align__(16) unsigned short h0h[kRows * HS];
  __shared__ __align__(16) unsigned short h1h[kRows * HS];
  __shared__ __align__(16) float yb[8][kRows * YS];  // 8-step output staging

  const int tid = threadIdx.x;
  const int wv = tid >> 6;    // wave: cols [32w,32w+32) (L0/L1), [16w,16w+16) (L2)
  const int lane = tid & 63;
  const int l15 = lane & 15;
  const int quad = lane >> 4;
  const int brow = blockIdx.x * kRows;
  const int rswz = (quad & 2) ? 2 : 0;  // writer chunk swizzle (rows = quad*4+r)
  const int asw = (l15 & 8) ? 2 : 0;    // A-frag reader chunk swizzle (row = l15)

  // ---- persistent split-weight fragments in VGPRs ----
  short8 w0fh[3][2], w0fl[3][2], w1fh[4][2], w1fl[4][2], w2fh[4], w2fl[4];
  {
    const int k0q = quad * 8;
#pragma unroll
    for (int kt = 0; kt < 3; ++kt)
#pragma unroll
      for (int nt = 0; nt < 2; ++nt) {
        short8 vh, vl;
        const int col = wv * 32 + nt * 16 + l15;
#pragma unroll
        for (int j = 0; j < 8; ++j) {
          int k = kt * 32 + k0q + j;
          unsigned short hi = 0, lo = 0;
          if (k < kKZ) split_bf(w0g[k * kH + col], hi, lo);  // zero-pad K 80->96
          vh[j] = (short)hi; vl[j] = (short)lo;
        }
        w0fh[kt][nt] = vh; w0fl[kt][nt] = vl;
      }
#pragma unroll
    for (int kt = 0; kt < 4; ++kt)
#pragma unroll
      for (int nt = 0; nt < 2; ++nt) {
        short8 vh, vl;
        const int col = wv * 32 + nt * 16 + l15;
#pragma unroll
        for (int j = 0; j < 8; ++j) {
          unsigned short hi, lo;
          split_bf(w1g[(kt * 32 + k0q + j) * kH + col], hi, lo);
          vh[j] = (short)hi; vl[j] = (short)lo;
        }
        w1fh[kt][nt] = vh; w1fl[kt][nt] = vl;
      }
#pragma unroll
    for (int kt = 0; kt < 4; ++kt) {
      short8 vh, vl;
      const int col = wv * 16 + l15;
#pragma unroll
      for (int j = 0; j < 8; ++j) {
        unsigned short hi, lo;
        split_bf(w2g[(kt * 32 + k0q + j) * kD + col], hi, lo);
        vh[j] = (short)hi; vl[j] = (short)lo;
      }
      w2fh[kt] = vh; w2fl[kt] = vl;
    }
  }
  float bias0[2], bias1[2];
#pragma unroll
  for (int nt = 0; nt < 2; ++nt) {
    bias0[nt] = b0g[wv * 32 + nt * 16 + l15];
    bias1[nt] = b1g[wv * 32 + nt * 16 + l15];
  }
  const float bias2 = b2g[wv * 16 + l15];
  const int colL2 = wv * 16 + l15;

  // ---- per-lane fp32 state registers (C/D layout: rows quad*4+r, col colL2) ----
  float stR[4], d1R[4];
#pragma unroll
  for (int r = 0; r < 4; ++r)
    stR[r] = xg[((size_t)(brow + quad * 4 + r) * kD + colL2) * kT];  // t = 0

  // ---- LDS init: z state cols (swizzled), zero p/pad region ----
  for (int idx = tid; idx < kRows * kD; idx += kThreads) {
    int r = idx >> 6, c = idx & 63;
    float xv = xg[((size_t)(brow + r) * kD + c) * kT];
    unsigned short hi, lo;
    split_bf(xv, hi, lo);
    int off = r * Z0S + ((((c >> 3) ^ ((r & 8) ? 2 : 0)) << 3) | (c & 7));
    zh[off] = hi;
    zl[off] = lo;
  }
  for (int idx = tid; idx < kRows * 40; idx += kThreads) {  // physical cols 64..103
    int r = idx / 40, c = idx % 40;
    zh[r * Z0S + kD + c] = 0;
    zl[r * Z0S + kD + c] = 0;
  }
  const int prow = tid >> 4, ppp = tid & 15;  // 16x16 map for p staging
  const size_t pbase = ((size_t)(brow + prow) * kP + ppp) * kT;
  const int poff = prow * Z0S + ((((8 + (ppp >> 3)) ^ ((prow & 8) ? 2 : 0)) << 3) | (ppp & 7));
  float pv = pg[pbase];  // p[..., 0]
  __syncthreads();

  for (int t = 0; t < kT; ++t) {
    {  // p columns of z (swizzled chunk)
      unsigned short hi, lo;
      split2(pv, hi, lo);
      zh[poff] = hi;
      zl[poff] = lo;
    }
    __syncthreads();  // z complete (state cols from prev step, p now)

    float pvn = 0.0f;
    if (t + 1 < kT) pvn = pg[pbase + t + 1];  // prefetch, hidden by the step

    if ((t & 7) == 0 && t) {  // burst previous 8-step output tile
      const int t0 = t - 8;
#pragma unroll
      for (int q2 = 0; q2 < 4; ++q2) {
        int idx = tid + q2 * kThreads;
        int r = idx >> 6, c = idx & 63;
        float v[8];
#pragma unroll
        for (int s = 0; s < 8; ++s) v[s] = yb[s][r * YS + c];
        float* dst = outg + ((size_t)(brow + r) * kD + c) * kT + t0;  // 16B-aligned
        float4v vlo = {v[0], v[1], v[2], v[3]}, vhi = {v[4], v[5], v[6], v[7]};
        *(float4v*)(dst) = vlo;
        *(float4v*)(dst + 4) = vhi;
      }
    }

#pragma unroll
    for (int ev = 0; ev < 2; ++ev) {  // Heun: eval1 at c, eval2 at c+d1
      // ---- L0: z[16x96] @ W0[96x128], full split (z is O(5)): 3 chains ----
      short8 a0h[3], a0l[3];
#pragma unroll
      for (int kt = 0; kt < 3; ++kt) {
        const int off = l15 * Z0S + (((kt * 4 + quad) ^ asw) << 3);
        a0h[kt] = *(const short8*)&zh[off];
        a0l[kt] = *(const short8*)&zl[off];
      }
#pragma unroll
      for (int nt = 0; nt < 2; ++nt) {
        float4v ahh = {bias0[nt], bias0[nt], bias0[nt], bias0[nt]};
        float4v ahl = {0.f, 0.f, 0.f, 0.f}, alh = {0.f, 0.f, 0.f, 0.f};
#pragma unroll
        for (int kt = 0; kt < 3; ++kt) {
          ahh = __builtin_amdgcn_mfma_f32_16x16x32_bf16(a0h[kt], w0fh[kt][nt], ahh, 0, 0, 0);
          ahl = __builtin_amdgcn_mfma_f32_16x16x32_bf16(a0h[kt], w0fl[kt][nt], ahl, 0, 0, 0);
          alh = __builtin_amdgcn_mfma_f32_16x16x32_bf16(a0l[kt], w0fh[kt][nt], alh, 0, 0, 0);
        }
        float4v ac = ahh + (ahl + alh);
        const int cb = wv * 4 + nt * 2 + (l15 >> 3);
        const int off = (((cb ^ rswz) << 3) | (l15 & 7));
#pragma unroll
        for (int r = 0; r < 4; ++r)
          h0h[(quad * 4 + r) * HS + off] = f2bf1(fast_tanh(ac[r]));
      }
      __syncthreads();
      // ---- L1: h0[16x128] @ W1[128x128], hi-activation + w-lo correction ----
      short8 a1h[4];
#pragma unroll
      for (int kt = 0; kt < 4; ++kt) {
        const int off = l15 * HS + (((kt * 4 + quad) ^ asw) << 3);
        a1h[kt] = *(const short8*)&h0h[off];
      }
#pragma unroll
      for (int nt = 0; nt < 2; ++nt) {
        float4v ahh = {bias1[nt], bias1[nt], bias1[nt], bias1[nt]};
        float4v ahl = {0.f, 0.f, 0.f, 0.f};
#pragma unroll
        for (int kt = 0; kt < 4; ++kt) {
          ahh = __builtin_amdgcn_mfma_f32_16x16x32_bf16(a1h[kt], w1fh[kt][nt], ahh, 0, 0, 0);
          ahl = __builtin_amdgcn_mfma_f32_16x16x32_bf16(a1h[kt], w1fl[kt][nt], ahl, 0, 0, 0);
        }
        float4v ac = ahh + ahl;
        const int cb = wv * 4 + nt * 2 + (l15 >> 3);
        const int off = (((cb ^ rswz) << 3) | (l15 & 7));
#pragma unroll
        for (int r = 0; r < 4; ++r)
          h1h[(quad * 4 + r) * HS + off] = f2bf1(fast_tanh(ac[r]));
      }
      __syncthreads();
      // ---- L2: h1[16x128] @ W2[128x64] (wave w -> cols [16w,16w+16)) ----
      short8 a2h[4];
#pragma unroll
      for (int kt = 0; kt < 4; ++kt) {
        const int off = l15 * HS + (((kt * 4 + quad) ^ asw) << 3);
        a2h[kt] = *(const short8*)&h1h[off];
      }
      float4v ahh = {bias2, bias2, bias2, bias2};
      float4v ahl = {0.f, 0.f, 0.f, 0.f};
#pragma unroll
      for (int kt = 0; kt < 4; ++kt) {
        ahh = __builtin_amdgcn_mfma_f32_16x16x32_bf16(a2h[kt], w2fh[kt], ahh, 0, 0, 0);
        ahl = __builtin_amdgcn_mfma_f32_16x16x32_bf16(a2h[kt], w2fl[kt], ahl, 0, 0, 0);
      }
      float4v ac = ahh + ahl;

      const int zcb = wv * 2 + (l15 >> 3);
      const int zoff = (((zcb ^ rswz) << 3) | (l15 & 7));
      if (ev == 0) {
#pragma unroll
        for (int r = 0; r < 4; ++r) {
          d1R[r] = ac[r];
          float xi = stR[r] + ac[r];  // dt = 1
          unsigned short hi, lo;
          split2(xi, hi, lo);
          zh[(quad * 4 + r) * Z0S + zoff] = hi;
          zl[(quad * 4 + r) * Z0S + zoff] = lo;
        }
        __syncthreads();  // xi visible to all waves for eval2's L0
      } else {
#pragma unroll
        for (int r = 0; r < 4; ++r) {
          float c = stR[r];
          float nx = c + 0.5f * (ac[r] + d1R[r]);
          yb[t & 7][(quad * 4 + r) * YS + colL2] = c;  // emit PREVIOUS state
          stR[r] = nx;
          unsigned short hi, lo;
          split2(nx, hi, lo);
          zh[(quad * 4 + r) * Z0S + zoff] = hi;
          zl[(quad * 4 + r) * Z0S + zoff] = lo;
        }
        // no barrier: next iteration's top sync covers these stores
      }
    }
    pv = pvn;
  }
  __syncthreads();
  // tail flush: t = 496..499 (slots 0..3 of the last tile)
  {
    const int t0 = (kT / 8) * 8;  // 496
#pragma unroll
    for (int q2 = 0; q2 < 4; ++q2) {
      int idx = tid + q2 * kThreads;
      int r = idx >> 6, c = idx & 63;
      float v[4];
#pragma unroll
      for (int s = 0; s < 4; ++s) v[s] = yb[s][r * YS + c];
      float* dst = outg + ((size_t)(brow + r) * kD + c) * kT + t0;
      float4v vv = {v[0], v[1], v[2], v[3]};
      *(float4v*)(dst) = vv;
    }
  }
}

}  // namespace

extern "C" void kernel_launch(void* const* d_in, const int* in_sizes, int n_in,
                              void* d_out, int out_size, void* d_ws, size_t ws_size,
                              hipStream_t stream) {
  const float* xg = (const float*)d_in[0];   // x [512,64,500]
  const float* pg = (const float*)d_in[1];   // p [512,16,500]
  // d_in[2] = i_ext (unused by Simple_MLP)
  const float* w0g = (const float*)d_in[3];  // W0 [80,128]
  const float* b0g = (const float*)d_in[4];  // b0 [128]
  const float* w1g = (const float*)d_in[5];  // W1 [128,128]
  const float* b1g = (const float*)d_in[6];  // b1 [128]
  const float* w2g = (const float*)d_in[7];  // W2 [128,64]
  const float* b2g = (const float*)d_in[8];  // b2 [64]
  float* outg = (float*)d_out;               // [512,64,500] fp32

  hipLaunchKernelGGL(node_kernel, dim3(kBlocks), dim3(kThreads), 0, stream,
                     xg, pg, w0g, b0g, w1g, b1g, w2g, b2g, outg);
}

// Round 5
// 1210.583 us; speedup vs baseline: 1.4554x; 1.0947x over previous
//
#include <hip/hip_runtime.h>

namespace {

constexpr int kB = 512, kD = 64, kP = 16, kT = 500, kH = 128;
constexpr int kKZ = 80;              // D + P (z width)
constexpr int kRows = 16;            // batch rows per block (one MFMA M-tile)
constexpr int kBlocks = kB / kRows;  // 32
constexpr int kThreads = 512;        // 8 waves -> 2 waves/SIMD (latency hiding)

// LDS row strides (u16 elements). Writes use a k-chunk XOR-2 swizzle for
// rows >= 8 so ds_write_b16 lands 2-way instead of 4-way.
constexpr int Z0S = 104;  // z planes: 12 used 16B chunks + pad
constexpr int HS = 136;   // h planes: 16 chunks + pad
constexpr int YS = 68;    // yb fp32 row stride

typedef __attribute__((ext_vector_type(8))) short short8;
typedef __attribute__((ext_vector_type(4))) float float4v;

__device__ __forceinline__ float bf2f(unsigned short u) {
  union { unsigned int i; float f; } v;
  v.i = ((unsigned int)u) << 16;
  return v.f;
}
__device__ __forceinline__ unsigned short f2bf(float f) {  // RNE
  union { float f; unsigned int i; } v;
  v.f = f;
  return (unsigned short)((v.i + 0x7FFFu + ((v.i >> 16) & 1u)) >> 16);
}
__device__ __forceinline__ void split_bf(float x, unsigned short& hi, unsigned short& lo) {
  hi = f2bf(x);
  lo = f2bf(x - bf2f(hi));
}
#if __has_builtin(__builtin_amdgcn_cvt_pk_bf16_f32)
__device__ __forceinline__ unsigned int pk_bf16(float a, float b) {
  auto v = __builtin_amdgcn_cvt_pk_bf16_f32(a, b);
  unsigned int u;
  __builtin_memcpy(&u, &v, 4);
  return u;
}
#else
__device__ __forceinline__ unsigned int pk_bf16(float a, float b) {
  return (unsigned int)f2bf(a) | ((unsigned int)f2bf(b) << 16);
}
#endif
__device__ __forceinline__ unsigned short f2bf1(float x) {  // 1-instr RNE round
  return (unsigned short)pk_bf16(x, x);
}
__device__ __forceinline__ void split2(float x, unsigned short& hi, unsigned short& lo) {
  unsigned int uh = pk_bf16(x, x);
  float hif;
  { unsigned int tb = uh << 16; __builtin_memcpy(&hif, &tb, 4); }
  hi = (unsigned short)uh;
  lo = (unsigned short)pk_bf16(x - hif, x - hif);
}
__device__ __forceinline__ float fast_tanh(float x) {
  // 1 - 2/(e^{2x}+1): exact saturation both ends, no NaN, 5 VALU.
  float e = __builtin_amdgcn_exp2f(x * 2.885390081777927f);  // 2*log2(e)
  return 1.0f - 2.0f * __builtin_amdgcn_rcpf(e + 1.0f);
}

// MFMA 16x16x32 bf16 layouts (gfx950):
//   A[m][k]: m = lane&15, k = (lane>>4)*8 + j
//   B[k][n]: n = lane&15, k = (lane>>4)*8 + j
//   C/D[m][n]: n = lane&15, m = (lane>>4)*4 + reg
__global__ __launch_bounds__(kThreads, 2) void node_kernel(
    const float* __restrict__ xg, const float* __restrict__ pg,
    const float* __restrict__ w0g, const float* __restrict__ b0g,
    const float* __restrict__ w1g, const float* __restrict__ b1g,
    const float* __restrict__ w2g, const float* __restrict__ b2g,
    float* __restrict__ outg) {
  __shared__ __align__(16) unsigned short zh[kRows * Z0S];
  __shared__ __align__(16) unsigned short zl[kRows * Z0S];
  __shared__ __align__(16) unsigned short h0h[kRows * HS];
  __shared__ __align__(16) unsigned short h1h[kRows * HS];
  __shared__ __align__(16) float yb[8][kRows * YS];  // 8-step output staging

  const int tid = threadIdx.x;
  const int wv = tid >> 6;    // wave 0..7: owns 16 cols of L0/L1; waves 0-3 own L2
  const int lane = tid & 63;
  const int l15 = lane & 15;
  const int quad = lane >> 4;
  const int brow = blockIdx.x * kRows;
  const int rswz = (quad & 2) ? 2 : 0;  // writer chunk swizzle (rows = quad*4+r)
  const int asw = (l15 & 8) ? 2 : 0;    // A-frag reader chunk swizzle (row = l15)

  const int col01 = wv * 16 + l15;        // L0/L1 output column of this wave
  const int colL2 = (wv & 3) * 16 + l15;  // L2 column (waves 4-7 duplicate loads, unused)

  // ---- persistent split-weight fragments in VGPRs ----
  // w0: z-part kt=0,1 (K 0..63); p-part kt=2 (K 64..95, zero-padded >=80)
  short8 w0fh[2], w0fl[2], w0pfh, w0pfl, w1fh[4], w1fl[4], w2fh[4], w2fl[4];
  {
    const int k0q = quad * 8;
#pragma unroll
    for (int kt = 0; kt < 2; ++kt) {
      short8 vh, vl;
#pragma unroll
      for (int j = 0; j < 8; ++j) {
        unsigned short hi, lo;
        split_bf(w0g[(kt * 32 + k0q + j) * kH + col01], hi, lo);
        vh[j] = (short)hi; vl[j] = (short)lo;
      }
      w0fh[kt] = vh; w0fl[kt] = vl;
    }
    {
      short8 vh, vl;
#pragma unroll
      for (int j = 0; j < 8; ++j) {
        int k = 64 + k0q + j;
        unsigned short hi = 0, lo = 0;
        if (k < kKZ) split_bf(w0g[k * kH + col01], hi, lo);
        vh[j] = (short)hi; vl[j] = (short)lo;
      }
      w0pfh = vh; w0pfl = vl;
    }
#pragma unroll
    for (int kt = 0; kt < 4; ++kt) {
      short8 vh, vl;
#pragma unroll
      for (int j = 0; j < 8; ++j) {
        unsigned short hi, lo;
        split_bf(w1g[(kt * 32 + k0q + j) * kH + col01], hi, lo);
        vh[j] = (short)hi; vl[j] = (short)lo;
      }
      w1fh[kt] = vh; w1fl[kt] = vl;
    }
#pragma unroll
    for (int kt = 0; kt < 4; ++kt) {
      short8 vh, vl;
#pragma unroll
      for (int j = 0; j < 8; ++j) {
        unsigned short hi, lo;
        split_bf(w2g[(kt * 32 + k0q + j) * kD + colL2], hi, lo);
        vh[j] = (short)hi; vl[j] = (short)lo;
      }
      w2fh[kt] = vh; w2fl[kt] = vl;
    }
  }
  const float bias0 = b0g[col01];
  const float bias1 = b1g[col01];
  const float bias2 = b2g[colL2];

  // ---- per-lane fp32 state registers (waves 0-3; C/D layout rows quad*4+r) ----
  float stR[4], d1R[4];
#pragma unroll
  for (int r = 0; r < 4; ++r)
    stR[r] = xg[((size_t)(brow + quad * 4 + r) * kD + colL2) * kT];  // t = 0

  // ---- LDS init: z state cols (swizzled), zero p/pad chunks 8..12 ----
  for (int idx = tid; idx < kRows * kD; idx += kThreads) {
    int r = idx >> 6, c = idx & 63;
    float xv = xg[((size_t)(brow + r) * kD + c) * kT];
    unsigned short hi, lo;
    split_bf(xv, hi, lo);
    int off = r * Z0S + ((((c >> 3) ^ ((r & 8) ? 2 : 0)) << 3) | (c & 7));
    zh[off] = hi;
    zl[off] = lo;
  }
  for (int idx = tid; idx < kRows * 40; idx += kThreads) {  // physical cols 64..103
    int r = idx / 40, c = idx % 40;
    zh[r * Z0S + kD + c] = 0;
    zl[r * Z0S + kD + c] = 0;
  }
  const int prow = (tid >> 4) & 15, ppp = tid & 15;  // 16x16 map (tid<256)
  const size_t pbase = ((size_t)(brow + prow) * kP + ppp) * kT;
  const int poff = prow * Z0S + ((((8 + (ppp >> 3)) ^ ((prow & 8) ? 2 : 0)) << 3) | (ppp & 7));
  float pv = (tid < 256) ? pg[pbase] : 0.0f;  // p[..., 0]
  __syncthreads();

  for (int t = 0; t < kT; ++t) {
    if (tid < 256) {  // p columns of z (swizzled chunk)
      unsigned short hi, lo;
      split2(pv, hi, lo);
      zh[poff] = hi;
      zl[poff] = lo;
    }
    __syncthreads();  // z complete (state cols from prev step, p now)

    float pvn = 0.0f;
    if (tid < 256 && t + 1 < kT) pvn = pg[pbase + t + 1];  // prefetch

    if ((t & 7) == 0 && t) {  // burst previous 8-step output tile
      const int t0 = t - 8;
#pragma unroll
      for (int q2 = 0; q2 < 2; ++q2) {
        int idx = tid + q2 * kThreads;
        int r = idx >> 6, c = idx & 63;
        float v[8];
#pragma unroll
        for (int s = 0; s < 8; ++s) v[s] = yb[s][r * YS + c];
        float* dst = outg + ((size_t)(brow + r) * kD + c) * kT + t0;  // 16B-aligned
        float4v vlo = {v[0], v[1], v[2], v[3]}, vhi = {v[4], v[5], v[6], v[7]};
        *(float4v*)(dst) = vlo;
        *(float4v*)(dst + 4) = vhi;
      }
    }

    // ---- step-invariant p-term: bias0 + z[64:96]*W0p (both Heun evals) ----
    float4v phh, phl, plh;
    {
      const int off = l15 * Z0S + (((8 + quad) ^ asw) << 3);
      short8 aph = *(const short8*)&zh[off];
      short8 apl = *(const short8*)&zl[off];
      float4v z4 = {0.f, 0.f, 0.f, 0.f};
      float4v b4 = {bias0, bias0, bias0, bias0};
      phh = __builtin_amdgcn_mfma_f32_16x16x32_bf16(aph, w0pfh, b4, 0, 0, 0);
      phl = __builtin_amdgcn_mfma_f32_16x16x32_bf16(aph, w0pfl, z4, 0, 0, 0);
      plh = __builtin_amdgcn_mfma_f32_16x16x32_bf16(apl, w0pfh, z4, 0, 0, 0);
    }

#pragma unroll
    for (int ev = 0; ev < 2; ++ev) {  // Heun: eval1 at c, eval2 at c+d1
      // ---- L0: z[16x64] @ W0z[64x16] + cached p-term; full split ----
      short8 a0h[2], a0l[2];
#pragma unroll
      for (int kt = 0; kt < 2; ++kt) {
        const int off = l15 * Z0S + (((kt * 4 + quad) ^ asw) << 3);
        a0h[kt] = *(const short8*)&zh[off];
        a0l[kt] = *(const short8*)&zl[off];
      }
      {
        float4v ahh = phh, ahl = phl, alh = plh;
#pragma unroll
        for (int kt = 0; kt < 2; ++kt) {
          ahh = __builtin_amdgcn_mfma_f32_16x16x32_bf16(a0h[kt], w0fh[kt], ahh, 0, 0, 0);
          ahl = __builtin_amdgcn_mfma_f32_16x16x32_bf16(a0h[kt], w0fl[kt], ahl, 0, 0, 0);
          alh = __builtin_amdgcn_mfma_f32_16x16x32_bf16(a0l[kt], w0fh[kt], alh, 0, 0, 0);
        }
        float4v ac = ahh + (ahl + alh);
        const int cb = wv * 2 + (l15 >> 3);
        const int off = (((cb ^ rswz) << 3) | (l15 & 7));
#pragma unroll
        for (int r = 0; r < 4; ++r)
          h0h[(quad * 4 + r) * HS + off] = f2bf1(fast_tanh(ac[r]));
      }
      __syncthreads();
      // ---- L1: h0[16x128] @ W1[128x16], hi-activation + w-lo correction ----
      short8 a1h[4];
#pragma unroll
      for (int kt = 0; kt < 4; ++kt) {
        const int off = l15 * HS + (((kt * 4 + quad) ^ asw) << 3);
        a1h[kt] = *(const short8*)&h0h[off];
      }
      {
        float4v ahh = {bias1, bias1, bias1, bias1};
        float4v ahl = {0.f, 0.f, 0.f, 0.f};
#pragma unroll
        for (int kt = 0; kt < 4; ++kt) {
          ahh = __builtin_amdgcn_mfma_f32_16x16x32_bf16(a1h[kt], w1fh[kt], ahh, 0, 0, 0);
          ahl = __builtin_amdgcn_mfma_f32_16x16x32_bf16(a1h[kt], w1fl[kt], ahl, 0, 0, 0);
        }
        float4v ac = ahh + ahl;
        const int cb = wv * 2 + (l15 >> 3);
        const int off = (((cb ^ rswz) << 3) | (l15 & 7));
#pragma unroll
        for (int r = 0; r < 4; ++r)
          h1h[(quad * 4 + r) * HS + off] = f2bf1(fast_tanh(ac[r]));
      }
      __syncthreads();
      // ---- L2: h1[16x128] @ W2[128x16] on waves 0-3 only ----
      float4v ac;
      if (wv < 4) {
        short8 a2h[4];
#pragma unroll
        for (int kt = 0; kt < 4; ++kt) {
          const int off = l15 * HS + (((kt * 4 + quad) ^ asw) << 3);
          a2h[kt] = *(const short8*)&h1h[off];
        }
        float4v ahh = {bias2, bias2, bias2, bias2};
        float4v ahl = {0.f, 0.f, 0.f, 0.f};
#pragma unroll
        for (int kt = 0; kt < 4; ++kt) {
          ahh = __builtin_amdgcn_mfma_f32_16x16x32_bf16(a2h[kt], w2fh[kt], ahh, 0, 0, 0);
          ahl = __builtin_amdgcn_mfma_f32_16x16x32_bf16(a2h[kt], w2fl[kt], ahl, 0, 0, 0);
        }
        ac = ahh + ahl;
      }

      const int zcb = (wv & 3) * 2 + (l15 >> 3);
      const int zoff = (((zcb ^ rswz) << 3) | (l15 & 7));
      if (ev == 0) {
        if (wv < 4) {
#pragma unroll
          for (int r = 0; r < 4; ++r) {
            d1R[r] = ac[r];
            float xi = stR[r] + ac[r];  // dt = 1
            unsigned short hi, lo;
            split2(xi, hi, lo);
            zh[(quad * 4 + r) * Z0S + zoff] = hi;
            zl[(quad * 4 + r) * Z0S + zoff] = lo;
          }
        }
        __syncthreads();  // xi visible to all waves for eval2's L0
      } else {
        if (wv < 4) {
#pragma unroll
          for (int r = 0; r < 4; ++r) {
            float c = stR[r];
            float nx = c + 0.5f * (ac[r] + d1R[r]);
            yb[t & 7][(quad * 4 + r) * YS + colL2] = c;  // emit PREVIOUS state
            stR[r] = nx;
            unsigned short hi, lo;
            split2(nx, hi, lo);
            zh[(quad * 4 + r) * Z0S + zoff] = hi;
            zl[(quad * 4 + r) * Z0S + zoff] = lo;
          }
        }
        // no barrier: next iteration's top sync covers these stores
      }
    }
    pv = pvn;
  }
  __syncthreads();
  // tail flush: t = 496..499 (slots 0..3 of the last tile)
  {
    const int t0 = (kT / 8) * 8;  // 496
#pragma unroll
    for (int q2 = 0; q2 < 2; ++q2) {
      int idx = tid + q2 * kThreads;
      int r = idx >> 6, c = idx & 63;
      float v[4];
#pragma unroll
      for (int s = 0; s < 4; ++s) v[s] = yb[s][r * YS + c];
      float* dst = outg + ((size_t)(brow + r) * kD + c) * kT + t0;
      float4v vv = {v[0], v[1], v[2], v[3]};
      *(float4v*)(dst) = vv;
    }
  }
}

}  // namespace

extern "C" void kernel_launch(void* const* d_in, const int* in_sizes, int n_in,
                              void* d_out, int out_size, void* d_ws, size_t ws_size,
                              hipStream_t stream) {
  const float* xg = (const float*)d_in[0];   // x [512,64,500]
  const float* pg = (const float*)d_in[1];   // p [512,16,500]
  // d_in[2] = i_ext (unused by Simple_MLP)
  const float* w0g = (const float*)d_in[3];  // W0 [80,128]
  const float* b0g = (const float*)d_in[4];  // b0 [128]
  const float* w1g = (const float*)d_in[5];  // W1 [128,128]
  const float* b1g = (const float*)d_in[6];  // b1 [128]
  const float* w2g = (const float*)d_in[7];  // W2 [128,64]
  const float* b2g = (const float*)d_in[8];  // b2 [64]
  float* outg = (float*)d_out;               // [512,64,500] fp32

  hipLaunchKernelGGL(node_kernel, dim3(kBlocks), dim3(kThreads), 0, stream,
                     xg, pg, w0g, b0g, w1g, b1g, w2g, b2g, outg);
}